// Round 19
// baseline (63.472 us; speedup 1.0000x reference)
//
#include <hip/hip_runtime.h>
#include <stdint.h>

// CorrelationLayer via MFMA Gram tiles — 3 blocks/CU via j-split + 16-px slab.
// out[j*7+i, h, w] = sum_c x[c,h,w] * y[c,h+j-3,w+i-3], zero-padded.
//
// R19 theory: occupancy has tracked dur all session (22%->83us, 40%->59us).
// Push 2 -> 3 blocks/CU: the 6-waves/SIMD tier needs <=85 combined regs.
// acc[7][2]=56 is the blocker -> j-split across waves (R10/R11-verified):
// kg=0 -> j 0..3, kg=1 -> j 4..6, acc[4][2]=32 AGPR + ~52 arch ~= 84 <= 85.
// Block = 512 thr / 8 waves = (dh 0..3, kg 0..1), 4 output rows x 16-px slab;
// NCOL=24 (cols ws-4..ws+19), LDS 19.2 KB -> 3 blocks/CU by LDS;
// __launch_bounds__(512,6) forces the reg tier (spill tell: WRITE >> 37.6).
// Tile1 only needs cols ws+13..ws+18 (LDS 17..22 < 24); lanes m>=6 clamp and
// produce unused G1 cols (extraction reads n = m+g+4-16 <= 5 only).
// All staging/fragment/extraction math byte-identical to R15/R18:
// col-pair staging (8x float2 -> pkbf -> 2x b128, kb-XOR swizzle
// kb^((c2>>2)&3), read-inverted g^((col>>3)&3)); A/B frag lane {m|n}=l&15,
// k=(l>>4)*8+e; C/D col=lane&15, row=(lane>>4)*4+reg; slab 16x34, i=g/g+4;
// af per-chunk (R18). Grid 96 hg x 32 slabs = 3072; XCD k owns hg [12k,12k+12).

typedef __attribute__((ext_vector_type(8))) short short8;
typedef __attribute__((ext_vector_type(4))) float floatx4;

constexpr int C = 128;
constexpr int H = 384;
constexpr int W = 512;
constexpr int HW = H * W;

constexpr int NROW = 10;              // rows h0-3 .. h0+6
constexpr int NCOL = 24;              // LDS col 0 = abs ws_blk - 4
constexpr int KP   = 40;              // bf16 per col (32 k + 8 pad) = 80 B
constexpr int ROWB = NCOL * KP * 2;   // 1920 B per row
constexpr int BUFE = NROW * NCOL * KP;        // 9600 bf16 elems (19.2 KB)
constexpr int NUNIT = NROW * 4 * (NCOL / 2);  // 480 staging units

__device__ __forceinline__ uint32_t pkbf(float a, float b) {
  uint32_t ua = (__float_as_uint(a) + 0x8000u) >> 16;
  uint32_t ub = (__float_as_uint(b) + 0x8000u) & 0xffff0000u;
  return ua | ub;
}

union S8U { uint32_t u[4]; short8 s; };

// stage one unit: (row, kb, col-pair) = 8 k-planes x 2 cols; inline
// load -> pack -> swizzled ds_write (nothing lives across compute phases).
__device__ __forceinline__ void stage_unit(const float* __restrict__ y,
                                           uint16_t* __restrict__ buf,
                                           int kc, int h0, int ws_blk, int u) {
  const int c2  = u % 12;
  const int kb  = (u / 12) & 3;
  const int row = u / 48;                    // 0..9
  const int r_abs = h0 - 3 + row;
  const int cb    = ws_blk - 4 + 2 * c2;     // even -> no pair straddle
  const bool val = (r_abs >= 0) & (r_abs < H) & (cb >= 0) & (cb <= W - 2);
  const int r  = r_abs < 0 ? 0 : (r_abs >= H ? H - 1 : r_abs);
  const int cc = cb < 0 ? 0 : (cb > W - 2 ? W - 2 : cb);
  const float* src = y + (size_t)(kc * 32 + kb * 8) * HW + (size_t)r * W + cc;
  float2 f[8];
#pragma unroll
  for (int e = 0; e < 8; ++e)
    f[e] = *reinterpret_cast<const float2*>(src + (size_t)e * HW);
  uint4 v0, v1;
  v0.x = pkbf(f[0].x, f[1].x); v0.y = pkbf(f[2].x, f[3].x);
  v0.z = pkbf(f[4].x, f[5].x); v0.w = pkbf(f[6].x, f[7].x);
  v1.x = pkbf(f[0].y, f[1].y); v1.y = pkbf(f[2].y, f[3].y);
  v1.z = pkbf(f[4].y, f[5].y); v1.w = pkbf(f[6].y, f[7].y);
  if (!val) { v0 = make_uint4(0, 0, 0, 0); v1 = make_uint4(0, 0, 0, 0); }
  const int kbs  = kb ^ ((c2 >> 2) & 3);     // bank swizzle (16B granule)
  const int ldso = (row * NCOL + 2 * c2) * KP + kbs * 8;
  *reinterpret_cast<uint4*>(&buf[ldso])      = v0;
  *reinterpret_cast<uint4*>(&buf[ldso + KP]) = v1;   // same quad -> same swz
}

__global__ __launch_bounds__(512, 6)
void corr_mfma(const float* __restrict__ x, const float* __restrict__ y,
               float* __restrict__ out) {
  __shared__ uint16_t ys[BUFE];              // 19200 B

  const int bid  = blockIdx.x;
  const int xcd  = bid & 7;
  const int idx  = bid >> 3;                 // 0..383
  const int hg   = xcd * 12 + (idx >> 5);    // 0..95
  const int slab = idx & 31;
  const int h0     = hg * 4;
  const int ws_blk = slab * 16;
  const int tid  = threadIdx.x;
  const int wv   = tid >> 6;                 // 0..7
  const int lane = tid & 63;
  const int m  = lane & 15;
  const int g  = lane >> 4;
  const int dh = wv >> 1;                    // 0..3
  const int kg = wv & 1;                     // j-split group
  const int h  = h0 + dh;
  const int ws = ws_blk;
  const int j0 = kg ? 4 : 0;
  const int nj = kg ? 3 : 4;

  const bool stg = (tid < NUNIT);            // 480 staging threads

  floatx4 acc[4][2];
#pragma unroll
  for (int jj = 0; jj < 4; ++jj) {
    acc[jj][0] = (floatx4){0.f, 0.f, 0.f, 0.f};
    acc[jj][1] = (floatx4){0.f, 0.f, 0.f, 0.f};
  }

  // per-lane b128 read byte-offsets within a row slab (swizzle-inverted)
  const int col0 = m + 1;                    // abs ws-3+m
  int col1 = col0 + 16;                      // tile1; clamp unused lanes
  if (col1 > NCOL - 1) col1 = NCOL - 1;
  const int fb0 = col0 * (KP * 2) + (g ^ ((col0 >> 3) & 3)) * 16;
  const int fb1 = col1 * (KP * 2) + (g ^ ((col1 >> 3) & 3)) * 16;

  const float* xb = x + (size_t)(g * 8) * HW + (size_t)h * W + (ws + m);

  // ---- main loop: stage -> (af load) -> barrier -> compute ----
#pragma unroll
  for (int kc = 0; kc < 4; ++kc) {
    if (kc) __syncthreads();                 // reads of previous chunk done
    if (stg) stage_unit(y, ys, kc, h0, ws_blk, tid);

    // A fragment for THIS chunk (x slice L1-resident after chunk 0;
    // issued during the staging phase, consumed after the barrier).
    short8 af;
    {
      float f[8];
#pragma unroll
      for (int e = 0; e < 8; ++e)
        f[e] = xb[(size_t)(kc * 32 + e) * HW];
      S8U s;
      s.u[0] = pkbf(f[0], f[1]);
      s.u[1] = pkbf(f[2], f[3]);
      s.u[2] = pkbf(f[4], f[5]);
      s.u[3] = pkbf(f[6], f[7]);
      af = s.s;
    }
    __syncthreads();

    // compute chunk kc: B row = dh + j, j = j0 + jj
#pragma unroll
    for (int jj = 0; jj < 4; ++jj) {
      if (jj < nj) {                         // wave-uniform guard
        const int j = j0 + jj;
        const uint8_t* rb =
            reinterpret_cast<const uint8_t*>(ys) + (dh + j) * ROWB;
        const short8 b0 = *reinterpret_cast<const short8*>(rb + fb0);
        const short8 b1 = *reinterpret_cast<const short8*>(rb + fb1);
        acc[jj][0] = __builtin_amdgcn_mfma_f32_16x16x32_bf16(af, b0, acc[jj][0], 0, 0, 0);
        acc[jj][1] = __builtin_amdgcn_mfma_f32_16x16x32_bf16(af, b1, acc[jj][1], 0, 0, 0);
      }
    }
  }

  // ---- extraction: per-wave 16x34 f32 slab (reuses ys; 8*2176B = 17.4KB) ----
  __syncthreads();
  float* slabp = reinterpret_cast<float*>(ys) + wv * 544;
#pragma unroll
  for (int jj = 0; jj < 4; ++jj) {
    if (jj < nj) {                           // wave-uniform guard
      const int j = j0 + jj;
#pragma unroll
      for (int q = 0; q < 4; ++q) {
        slabp[(g * 4 + q) * 34 + m]      = acc[jj][0][q];   // cols 0..15
        slabp[(g * 4 + q) * 34 + 16 + m] = acc[jj][1][q];   // cols 16..31
      }
      const float vo0 = slabp[m * 34 + m + g];              // i = g
      const float vo1 = slabp[m * 34 + m + g + 4];          // i = g+4 (g<3)
      float* ob = out + (size_t)(j * 7 + g) * HW + (size_t)h * W + (ws + m);
      *ob = vo0;
      if (g < 3) ob[(size_t)4 * HW] = vo1;
    }
  }
}

extern "C" void kernel_launch(void* const* d_in, const int* in_sizes, int n_in,
                              void* d_out, int out_size, void* d_ws, size_t ws_size,
                              hipStream_t stream) {
  const float* x = (const float*)d_in[0];
  const float* y = (const float*)d_in[1];
  float* out = (float*)d_out;
  corr_mfma<<<dim3(96 * 32), dim3(512), 0, stream>>>(x, y, out);
}

// Round 20
// 59.407 us; speedup vs baseline: 1.0684x; 1.0684x over previous
//
#include <hip/hip_runtime.h>
#include <stdint.h>

// CorrelationLayer via MFMA Gram tiles — R18 + balanced single-burst staging.
// out[j*7+i, h, w] = sum_c x[c,h,w] * y[c,h+j-3,w+i-3], zero-padded.
//
// R20 = R18 (best: 59.1us; 512 thr / 8 waves = 4 output rows x 32-px slab,
// NROW=10, LDS 32KB, 2 blocks/CU at the 128-reg tier) with staging switched
// from 800 col-PAIR units (288 threads run 2 serial units -> 2nd unit's
// loads wait on 1st unit's vmcnt drain) to 400 col-QUAD units: exactly
// <=1 unit/thread, 8x float4 issued as ONE parallel burst per thread.
// Reg check (R14 lesson): burst 32 VGPR transient; persistent = acc 56 AGPR
// + af 4 + addr ~20 -> ~124 combined <= 128. Spill tell: WRITE >> 37.6 MB.
// Quad swizzle: cols 4c4..4c4+3 share (col>>3) so one kbs = kb^((c4>>1)&3)
// serves all 4 b128 writes; read inversion g^((col>>3)&3) unchanged.
// All other math byte-identical to R18 (verified): A/B frag lane {m|n}=l&15,
// k=(l>>4)*8+e; C/D col=lane&15, row=(lane>>4)*4+reg; af per-chunk;
// extraction slab 16x34 f32, i=g / g+4 (g<3).
// R19 lesson: occupancy 62% at 16-px slabs LOST to staging redundancy —
// do not shrink slabs further.
// Grid 96 hg x 16 slabs = 1536; XCD k owns hg [12k,12k+12), slab-fastest.

typedef __attribute__((ext_vector_type(8))) short short8;
typedef __attribute__((ext_vector_type(4))) float floatx4;

constexpr int C = 128;
constexpr int H = 384;
constexpr int W = 512;
constexpr int HW = H * W;

constexpr int NROW = 10;              // rows h0-3 .. h0+6
constexpr int NCOL = 40;              // LDS col 0 = abs ws_blk - 4
constexpr int KP   = 40;              // bf16 per col (32 k + 8 pad) = 80 B
constexpr int ROWB = NCOL * KP * 2;   // 3200 B per row
constexpr int BUFE = NROW * NCOL * KP;        // 16000 bf16 elems (32 KB)
constexpr int NUNIT = NROW * 4 * (NCOL / 4);  // 400 staging units

__device__ __forceinline__ uint32_t pkbf(float a, float b) {
  uint32_t ua = (__float_as_uint(a) + 0x8000u) >> 16;
  uint32_t ub = (__float_as_uint(b) + 0x8000u) & 0xffff0000u;
  return ua | ub;
}

union S8U { uint32_t u[4]; short8 s; };

// stage one unit: (row, kb, col-quad) = 8 k-planes x 4 cols; one parallel
// 8x float4 burst -> pack -> 4x swizzled b128 writes. Nothing lives across
// compute phases.
__device__ __forceinline__ void stage_unit(const float* __restrict__ y,
                                           uint16_t* __restrict__ buf,
                                           int kc, int h0, int ws_blk, int u) {
  const int c4  = u % 10;
  const int kb  = (u / 10) & 3;
  const int row = u / 40;                    // 0..9
  const int r_abs = h0 - 3 + row;
  const int cb    = ws_blk - 4 + 4 * c4;     // mult of 4 -> no quad straddle
  const bool val = (r_abs >= 0) & (r_abs < H) & (cb >= 0) & (cb <= W - 4);
  const int r  = r_abs < 0 ? 0 : (r_abs >= H ? H - 1 : r_abs);
  const int cc = cb < 0 ? 0 : (cb > W - 4 ? W - 4 : cb);
  const float* src = y + (size_t)(kc * 32 + kb * 8) * HW + (size_t)r * W + cc;
  float4 f[8];
#pragma unroll
  for (int e = 0; e < 8; ++e)
    f[e] = *reinterpret_cast<const float4*>(src + (size_t)e * HW);
  uint4 v[4];
  v[0].x = pkbf(f[0].x, f[1].x); v[0].y = pkbf(f[2].x, f[3].x);
  v[0].z = pkbf(f[4].x, f[5].x); v[0].w = pkbf(f[6].x, f[7].x);
  v[1].x = pkbf(f[0].y, f[1].y); v[1].y = pkbf(f[2].y, f[3].y);
  v[1].z = pkbf(f[4].y, f[5].y); v[1].w = pkbf(f[6].y, f[7].y);
  v[2].x = pkbf(f[0].z, f[1].z); v[2].y = pkbf(f[2].z, f[3].z);
  v[2].z = pkbf(f[4].z, f[5].z); v[2].w = pkbf(f[6].z, f[7].z);
  v[3].x = pkbf(f[0].w, f[1].w); v[3].y = pkbf(f[2].w, f[3].w);
  v[3].z = pkbf(f[4].w, f[5].w); v[3].w = pkbf(f[6].w, f[7].w);
  if (!val) {
#pragma unroll
    for (int q = 0; q < 4; ++q) v[q] = make_uint4(0, 0, 0, 0);
  }
  // cols 4c4..4c4+3 share (col>>3) -> single swizzle for the whole quad
  const int kbs  = kb ^ ((c4 >> 1) & 3);
  const int ldso = (row * NCOL + 4 * c4) * KP + kbs * 8;
#pragma unroll
  for (int q = 0; q < 4; ++q)
    *reinterpret_cast<uint4*>(&buf[ldso + q * KP]) = v[q];
}

__global__ __launch_bounds__(512, 4)
void corr_mfma(const float* __restrict__ x, const float* __restrict__ y,
               float* __restrict__ out) {
  __shared__ uint16_t ys[BUFE];              // 32000 B

  const int bid  = blockIdx.x;
  const int xcd  = bid & 7;
  const int idx  = bid >> 3;                 // 0..191
  const int hg   = xcd * 12 + (idx >> 4);    // 0..95
  const int slab = idx & 15;
  const int h0     = hg * 4;
  const int ws_blk = slab * 32;
  const int tid  = threadIdx.x;
  const int wv   = tid >> 6;                 // 0..7
  const int lane = tid & 63;
  const int m  = lane & 15;
  const int g  = lane >> 4;
  const int dh = wv >> 1;                    // 0..3
  const int ww = wv & 1;                     // 0..1
  const int h  = h0 + dh;
  const int ws = ws_blk + ww * 16;

  const bool stg = (tid < NUNIT);            // 400 staging threads

  floatx4 acc[7][2];
#pragma unroll
  for (int j = 0; j < 7; ++j) {
    acc[j][0] = (floatx4){0.f, 0.f, 0.f, 0.f};
    acc[j][1] = (floatx4){0.f, 0.f, 0.f, 0.f};
  }

  // per-lane b128 read byte-offsets within a row slab (swizzle-inverted)
  const int col0 = ww * 16 + m + 1;          // abs ws-3+m
  int col1 = col0 + 16;                      // tile1; clamp unused lanes
  if (col1 > NCOL - 1) col1 = NCOL - 1;
  const int fb0 = col0 * (KP * 2) + (g ^ ((col0 >> 3) & 3)) * 16;
  const int fb1 = col1 * (KP * 2) + (g ^ ((col1 >> 3) & 3)) * 16;

  const float* xb = x + (size_t)(g * 8) * HW + (size_t)h * W + (ws + m);

  // ---- main loop: stage -> (af load) -> barrier -> compute ----
#pragma unroll
  for (int kc = 0; kc < 4; ++kc) {
    if (kc) __syncthreads();                 // reads of previous chunk done
    if (stg) stage_unit(y, ys, kc, h0, ws_blk, tid);

    // A fragment for THIS chunk (x slice L1-resident after chunk 0;
    // issued during the staging phase, consumed after the barrier).
    short8 af;
    {
      float f[8];
#pragma unroll
      for (int e = 0; e < 8; ++e)
        f[e] = xb[(size_t)(kc * 32 + e) * HW];
      S8U s;
      s.u[0] = pkbf(f[0], f[1]);
      s.u[1] = pkbf(f[2], f[3]);
      s.u[2] = pkbf(f[4], f[5]);
      s.u[3] = pkbf(f[6], f[7]);
      af = s.s;
    }
    __syncthreads();

    // compute chunk kc: B row = dh + j
#pragma unroll
    for (int j = 0; j < 7; ++j) {
      const uint8_t* rb =
          reinterpret_cast<const uint8_t*>(ys) + (dh + j) * ROWB;
      const short8 b0 = *reinterpret_cast<const short8*>(rb + fb0);
      const short8 b1 = *reinterpret_cast<const short8*>(rb + fb1);
      acc[j][0] = __builtin_amdgcn_mfma_f32_16x16x32_bf16(af, b0, acc[j][0], 0, 0, 0);
      acc[j][1] = __builtin_amdgcn_mfma_f32_16x16x32_bf16(af, b1, acc[j][1], 0, 0, 0);
    }
  }

  // ---- extraction: per-wave 16x34 f32 slab (reuses ys; 8*2176B fits) ----
  __syncthreads();
  float* slabp = reinterpret_cast<float*>(ys) + wv * 544;
#pragma unroll
  for (int j = 0; j < 7; ++j) {
#pragma unroll
    for (int q = 0; q < 4; ++q) {
      slabp[(g * 4 + q) * 34 + m]      = acc[j][0][q];   // cols 0..15
      slabp[(g * 4 + q) * 34 + 16 + m] = acc[j][1][q];   // cols 16..31
    }
    const float vo0 = slabp[m * 34 + m + g];             // i = g
    const float vo1 = slabp[m * 34 + m + g + 4];         // i = g+4 (g<3)
    float* ob = out + (size_t)(j * 7 + g) * HW + (size_t)h * W + (ws + m);
    *ob = vo0;
    if (g < 3) ob[(size_t)4 * HW] = vo1;
  }
}

extern "C" void kernel_launch(void* const* d_in, const int* in_sizes, int n_in,
                              void* d_out, int out_size, void* d_ws, size_t ws_size,
                              hipStream_t stream) {
  const float* x = (const float*)d_in[0];
  const float* y = (const float*)d_in[1];
  float* out = (float*)d_out;
  corr_mfma<<<dim3(96 * 16), dim3(512), 0, stream>>>(x, y, out);
}

// Round 21
// 54.926 us; speedup vs baseline: 1.1556x; 1.0816x over previous
//
#include <hip/hip_runtime.h>
#include <stdint.h>

// CorrelationLayer via MFMA Gram tiles — R18 + LDS double-buffer + issue-early.
// out[j*7+i, h, w] = sum_c x[c,h,w] * y[c,h+j-3,w+i-3], zero-padded.
//
// R21 = R18 (59.1us champion: 512 thr / 8 waves = 4 output rows x 32-px slab,
// NROW=10, 2 blocks/CU at the 128-reg tier) + within-wave overlap:
//  - LDS double buffer (2x32KB = 64KB; 2 blocks/CU = 128KB <= 160KB).
//  - per chunk: issue unit-1 loads (8x float2 = 16 regs) + next-af floats
//    (8 regs) -> compute(kc) from buf[cur] (covers ~400cy load latency) ->
//    pack/write into buf[nxt] -> ONE barrier (R18: two barriers/chunk).
//  - 288 has2 threads stage their 2nd unit plainly in the write region
//    (exposed; covered by the co-resident block).
// Reg budget: held 24-28 + persistent ~45 arch + 56 AGPR ~= 125-130, at the
// tier edge by design. Spill tell: WRITE >> 37.6 MB. Sink tell: VGPR ~52.
// All math byte-identical to R18: col-pair staging (8x float2 -> pkbf ->
// 2x b128, kb-XOR swizzle kb^((c2>>2)&3), read-inverted g^((col>>3)&3));
// A/B frag lane {m|n}=l&15, k=(l>>4)*8+e; C/D col=lane&15,row=(lane>>4)*4+reg;
// af per-chunk; extraction slab 16x34 f32, i=g / g+4 (g<3).
// Grid 96 hg x 16 slabs = 1536; XCD k owns hg [12k,12k+12), slab-fastest.

typedef __attribute__((ext_vector_type(8))) short short8;
typedef __attribute__((ext_vector_type(4))) float floatx4;

constexpr int C = 128;
constexpr int H = 384;
constexpr int W = 512;
constexpr int HW = H * W;

constexpr int NROW = 10;              // rows h0-3 .. h0+6
constexpr int NCOL = 40;              // LDS col 0 = abs ws_blk - 4
constexpr int KP   = 40;              // bf16 per col (32 k + 8 pad) = 80 B
constexpr int ROWB = NCOL * KP * 2;   // 3200 B per row
constexpr int BUFE = NROW * NCOL * KP;        // 16000 bf16 elems (32 KB)
constexpr int NUNIT = NROW * 4 * (NCOL / 2);  // 800 staging units

__device__ __forceinline__ uint32_t pkbf(float a, float b) {
  uint32_t ua = (__float_as_uint(a) + 0x8000u) >> 16;
  uint32_t ub = (__float_as_uint(b) + 0x8000u) & 0xffff0000u;
  return ua | ub;
}

union S8U { uint32_t u[4]; short8 s; };

// decode staging unit u -> source pointer, validity, LDS element offset
__device__ __forceinline__ void unit_decode(const float* __restrict__ y,
                                            int kc, int h0, int ws_blk, int u,
                                            const float*& src, bool& val,
                                            int& ldso) {
  const int c2  = u % 20;
  const int kb  = (u / 20) & 3;
  const int row = u / 80;                    // 0..9
  const int r_abs = h0 - 3 + row;
  const int cb    = ws_blk - 4 + 2 * c2;     // even -> no pair straddle
  val = (r_abs >= 0) & (r_abs < H) & (cb >= 0) & (cb <= W - 2);
  const int r  = r_abs < 0 ? 0 : (r_abs >= H ? H - 1 : r_abs);
  const int cc = cb < 0 ? 0 : (cb > W - 2 ? W - 2 : cb);
  src = y + (size_t)(kc * 32 + kb * 8) * HW + (size_t)r * W + cc;
  const int kbs = kb ^ ((c2 >> 2) & 3);      // bank swizzle (16B granule)
  ldso = (row * NCOL + 2 * c2) * KP + kbs * 8;
}

__device__ __forceinline__ void unit_store(uint16_t* __restrict__ buf,
                                           const float2 f[8], bool val,
                                           int ldso) {
  uint4 v0, v1;
  v0.x = pkbf(f[0].x, f[1].x); v0.y = pkbf(f[2].x, f[3].x);
  v0.z = pkbf(f[4].x, f[5].x); v0.w = pkbf(f[6].x, f[7].x);
  v1.x = pkbf(f[0].y, f[1].y); v1.y = pkbf(f[2].y, f[3].y);
  v1.z = pkbf(f[4].y, f[5].y); v1.w = pkbf(f[6].y, f[7].y);
  if (!val) { v0 = make_uint4(0, 0, 0, 0); v1 = make_uint4(0, 0, 0, 0); }
  *reinterpret_cast<uint4*>(&buf[ldso])      = v0;
  *reinterpret_cast<uint4*>(&buf[ldso + KP]) = v1;   // same quad -> same swz
}

__device__ __forceinline__ void stage_plain(const float* __restrict__ y,
                                            uint16_t* __restrict__ buf,
                                            int kc, int h0, int ws_blk, int u) {
  const float* src; bool val; int ldso;
  unit_decode(y, kc, h0, ws_blk, u, src, val, ldso);
  float2 f[8];
#pragma unroll
  for (int e = 0; e < 8; ++e)
    f[e] = *reinterpret_cast<const float2*>(src + (size_t)e * HW);
  unit_store(buf, f, val, ldso);
}

__global__ __launch_bounds__(512, 4)
void corr_mfma(const float* __restrict__ x, const float* __restrict__ y,
               float* __restrict__ out) {
  __shared__ uint16_t ys[2][BUFE];           // 64000 B

  const int bid  = blockIdx.x;
  const int xcd  = bid & 7;
  const int idx  = bid >> 3;                 // 0..191
  const int hg   = xcd * 12 + (idx >> 4);    // 0..95
  const int slab = idx & 15;
  const int h0     = hg * 4;
  const int ws_blk = slab * 32;
  const int tid  = threadIdx.x;
  const int wv   = tid >> 6;                 // 0..7
  const int lane = tid & 63;
  const int m  = lane & 15;
  const int g  = lane >> 4;
  const int dh = wv >> 1;                    // 0..3
  const int ww = wv & 1;                     // 0..1
  const int h  = h0 + dh;
  const int ws = ws_blk + ww * 16;

  const bool has2 = (tid < NUNIT - 512);     // 288 threads own a 2nd unit

  floatx4 acc[7][2];
#pragma unroll
  for (int j = 0; j < 7; ++j) {
    acc[j][0] = (floatx4){0.f, 0.f, 0.f, 0.f};
    acc[j][1] = (floatx4){0.f, 0.f, 0.f, 0.f};
  }

  // per-lane b128 read byte-offsets within a row slab (swizzle-inverted)
  const int col0 = ww * 16 + m + 1;          // abs ws-3+m
  int col1 = col0 + 16;                      // tile1; clamp unused lanes
  if (col1 > NCOL - 1) col1 = NCOL - 1;
  const int fb0 = col0 * (KP * 2) + (g ^ ((col0 >> 3) & 3)) * 16;
  const int fb1 = col1 * (KP * 2) + (g ^ ((col1 >> 3) & 3)) * 16;

  const float* xb = x + (size_t)(g * 8) * HW + (size_t)h * W + (ws + m);

  // ---- prologue: stage chunk 0 into ys[0]; af for chunk 0 ----
  stage_plain(y, ys[0], 0, h0, ws_blk, tid);
  if (has2) stage_plain(y, ys[0], 0, h0, ws_blk, 512 + tid);
  short8 af_cur;
  {
    float f[8];
#pragma unroll
    for (int e = 0; e < 8; ++e) f[e] = xb[(size_t)e * HW];
    S8U s;
    s.u[0] = pkbf(f[0], f[1]);
    s.u[1] = pkbf(f[2], f[3]);
    s.u[2] = pkbf(f[4], f[5]);
    s.u[3] = pkbf(f[6], f[7]);
    af_cur = s.s;
  }
  __syncthreads();

  // ---- main loop: issue(kc+1) -> compute(kc) -> write(kc+1) -> barrier ----
#pragma unroll
  for (int kc = 0; kc < 4; ++kc) {
    // (1) issue next chunk's unit-1 loads + next af floats (held in regs)
    float2 F[8];
    float axf[8];
    bool v = false; int o = 0;
    if (kc < 3) {
      const float* s1;
      unit_decode(y, kc + 1, h0, ws_blk, tid, s1, v, o);
#pragma unroll
      for (int e = 0; e < 8; ++e)
        F[e] = *reinterpret_cast<const float2*>(s1 + (size_t)e * HW);
#pragma unroll
      for (int e = 0; e < 8; ++e)
        axf[e] = xb[(size_t)((kc + 1) * 32 + e) * HW];
    }

    // (2) compute chunk kc from ys[kc&1]: B row = dh + j
    const uint16_t* buf = ys[kc & 1];
#pragma unroll
    for (int j = 0; j < 7; ++j) {
      const uint8_t* rb =
          reinterpret_cast<const uint8_t*>(buf) + (dh + j) * ROWB;
      const short8 b0 = *reinterpret_cast<const short8*>(rb + fb0);
      const short8 b1 = *reinterpret_cast<const short8*>(rb + fb1);
      acc[j][0] = __builtin_amdgcn_mfma_f32_16x16x32_bf16(af_cur, b0, acc[j][0], 0, 0, 0);
      acc[j][1] = __builtin_amdgcn_mfma_f32_16x16x32_bf16(af_cur, b1, acc[j][1], 0, 0, 0);
    }

    // (3) write next chunk into ys[(kc+1)&1]; has2 unit staged plainly
    if (kc < 3) {
      uint16_t* nbuf = ys[(kc + 1) & 1];
      unit_store(nbuf, F, v, o);
      if (has2) stage_plain(y, nbuf, kc + 1, h0, ws_blk, 512 + tid);
      S8U s;
      s.u[0] = pkbf(axf[0], axf[1]);
      s.u[1] = pkbf(axf[2], axf[3]);
      s.u[2] = pkbf(axf[4], axf[5]);
      s.u[3] = pkbf(axf[6], axf[7]);
      af_cur = s.s;
    }
    __syncthreads();
  }

  // ---- extraction: per-wave 16x34 f32 slab (reuses ys[0]; 8*2176B fits) ----
  float* slabp = reinterpret_cast<float*>(&ys[0][0]) + wv * 544;
#pragma unroll
  for (int j = 0; j < 7; ++j) {
#pragma unroll
    for (int q = 0; q < 4; ++q) {
      slabp[(g * 4 + q) * 34 + m]      = acc[j][0][q];   // cols 0..15
      slabp[(g * 4 + q) * 34 + 16 + m] = acc[j][1][q];   // cols 16..31
    }
    const float vo0 = slabp[m * 34 + m + g];             // i = g
    const float vo1 = slabp[m * 34 + m + g + 4];         // i = g+4 (g<3)
    float* ob = out + (size_t)(j * 7 + g) * HW + (size_t)h * W + (ws + m);
    *ob = vo0;
    if (g < 3) ob[(size_t)4 * HW] = vo1;
  }
}

extern "C" void kernel_launch(void* const* d_in, const int* in_sizes, int n_in,
                              void* d_out, int out_size, void* d_ws, size_t ws_size,
                              hipStream_t stream) {
  const float* x = (const float*)d_in[0];
  const float* y = (const float*)d_in[1];
  float* out = (float*)d_out;
  corr_mfma<<<dim3(96 * 16), dim3(512), 0, stream>>>(x, y, out);
}